// Round 9
// baseline (335.810 us; speedup 1.0000x reference)
//
#include <hip/hip_runtime.h>

#define N_NODES   50000
#define MP        50048          // rows padded to 128
#define IN_DIM    16
#define CONCAT    496
#define K2        512            // padded K for GEMM1
#define HID       512
#define OUT_DIM   64
#define RDIM      16
#define NEDGE     800000
#define SCAN_B    196            // ceil(50000/256)
#define G1_NT     ((MP / 128) * 4)   // 1564 gemm1 tiles

typedef __attribute__((ext_vector_type(8))) short bf16x8;
typedef __attribute__((ext_vector_type(4))) float f32x4;

static __device__ __forceinline__ unsigned short f2bf(float x) {
    union { float f; unsigned u; } v; v.f = x;
    unsigned r = v.u + 0x7fff + ((v.u >> 16) & 1);
    return (unsigned short)(r >> 16);
}
static __device__ __forceinline__ float bf2f(unsigned short b) {
    union { unsigned u; float f; } v; v.u = ((unsigned)b) << 16; return v.f;
}
static __device__ __forceinline__ unsigned packbf2(float a, float b) {
    return (unsigned)f2bf(a) | ((unsigned)f2bf(b) << 16);
}
static __device__ __forceinline__ float2 decw(int wbi) {
    unsigned wb = (unsigned)wbi;
    float w = __uint_as_float(wb & 0x7fffffffu);
    return (wb >> 31) ? make_float2(0.f, w) : make_float2(w, 0.f);
}

#define GLDS16(gp, lp) \
    __builtin_amdgcn_global_load_lds((const __attribute__((address_space(1))) unsigned int*)(gp), \
                                     (__attribute__((address_space(3))) unsigned int*)(lp), 16, 0, 0)

// ---- init: feature -> hb bf16; zero pads/stats/deg; W1 -> bf16 -------------------
__global__ __launch_bounds__(256) void k_init(const float* __restrict__ feat,
                                              const float* __restrict__ W1,
                                              unsigned short* __restrict__ hb,
                                              unsigned short* __restrict__ W1b,
                                              float* __restrict__ stats,
                                              int* __restrict__ deg) {
    int idx = blockIdx.x * blockDim.x + threadIdx.x;
    if (idx < 1024) stats[idx] = 0.f;
    if (idx < N_NODES) deg[idx] = 0;
    if (idx < HID * K2) {                          // W1 -> bf16, K-padded
        int n = idx >> 9, k = idx & 511;
        W1b[idx] = (k < CONCAT) ? f2bf(W1[n * CONCAT + k]) : (unsigned short)0;
    }
    if (idx < (MP - N_NODES) * K2) {               // zero padded rows of hb
        int r = N_NODES + (idx >> 9), c = idx & 511;
        hb[(long)r * K2 + c] = 0;
    }
    if (idx >= MP * IN_DIM) return;
    int n = idx >> 4, c = idx & 15;
    hb[(long)n * K2 + CONCAT + c] = 0;             // K pad cols 496..511
    if (n < N_NODES) hb[(long)n * K2 + c] = f2bf(feat[idx]);
}

// ---- CSR build: hist also emits per-edge rank within its dst bucket --------------
__global__ __launch_bounds__(256) void k_hist(const int* __restrict__ ei,
                                              int* __restrict__ deg,
                                              int* __restrict__ rank) {
    int e = blockIdx.x * blockDim.x + threadIdx.x;
    if (e < NEDGE) rank[e] = atomicAdd(&deg[ei[NEDGE + e]], 1);
}

__global__ __launch_bounds__(256) void k_scanA(const int* __restrict__ deg,
                                               int* __restrict__ bsum) {
    __shared__ int red[256];
    int t = threadIdx.x;
    int i = blockIdx.x * 256 + t;
    red[t] = (i < N_NODES) ? deg[i] : 0;
    __syncthreads();
    for (int d = 128; d > 0; d >>= 1) {
        if (t < d) red[t] += red[t + d];
        __syncthreads();
    }
    if (t == 0) bsum[blockIdx.x] = red[0];
}

__global__ __launch_bounds__(256) void k_scanB(const int* __restrict__ bsum,
                                               int* __restrict__ boff) {
    __shared__ int s[256];
    int t = threadIdx.x;
    s[t] = (t < SCAN_B) ? bsum[t] : 0;
    __syncthreads();
    for (int d = 1; d < 256; d <<= 1) {
        int v = (t >= d) ? s[t - d] : 0;
        __syncthreads();
        s[t] += v;
        __syncthreads();
    }
    boff[t] = (t > 0) ? s[t - 1] : 0;
}

__global__ __launch_bounds__(256) void k_scanC(const int* __restrict__ deg,
                                               const int* __restrict__ boff,
                                               int* __restrict__ rowptr) {
    __shared__ int s[256];
    int t = threadIdx.x;
    int i = blockIdx.x * 256 + t;
    int v = (i < N_NODES) ? deg[i] : 0;
    s[t] = v;
    __syncthreads();
    for (int d = 1; d < 256; d <<= 1) {
        int x = (t >= d) ? s[t - d] : 0;
        __syncthreads();
        s[t] += x;
        __syncthreads();
    }
    int excl = s[t] - v + boff[blockIdx.x];
    if (i < N_NODES) rowptr[i] = excl;
    if (i == N_NODES - 1) rowptr[N_NODES] = excl + v;
}

// ---- edge scatter: pos = rowptr[dst] + rank[e]; 8B packed record -----------------
__global__ __launch_bounds__(256) void k_scat(const int* __restrict__ ei,
                                              const float* __restrict__ ew,
                                              const int* __restrict__ et,
                                              const int* __restrict__ rank,
                                              const int* __restrict__ rowptr,
                                              int2* __restrict__ ed8) {
    int e = blockIdx.x * blockDim.x + threadIdx.x;
    if (e >= NEDGE) return;
    int dst = ei[NEDGE + e];
    unsigned wb = (__float_as_uint(ew[e]) & 0x7fffffffu) | ((unsigned)et[e] << 31);
    ed8[rowptr[dst] + rank[e]] = make_int2(ei[e], (int)wb);
}

// ---- gather (bf16 in/out): G lanes per dst, 2 bf16/lane (4B packed); unroll-4 ----
template<int D, int OFF_IN, int OFFB, int G>
__global__ __launch_bounds__(256) void k_gather_bf(const int* __restrict__ rowptr,
                                                   const int2* __restrict__ ed8,
                                                   unsigned short* __restrict__ hb) {
    const int NPB = 256 / G;
    int node = blockIdx.x * NPB + threadIdx.x / G;
    if (node >= N_NODES) return;
    int lane = threadIdx.x % G;
    int p0 = rowptr[node], p1 = rowptr[node + 1];
    float a00 = 0.f, a01 = 0.f, a10 = 0.f, a11 = 0.f;   // a{type}{elem}
    float c00 = 0.f, c01 = 0.f, c10 = 0.f, c11 = 0.f;
    const unsigned short* hin = hb + OFF_IN + lane * 2;
    int p = p0;
    for (; p + 4 <= p1; p += 4) {
        int2 E0 = ed8[p], E1 = ed8[p + 1], E2 = ed8[p + 2], E3 = ed8[p + 3];
        unsigned u0 = *(const unsigned*)(hin + (long)E0.x * K2);
        unsigned u1 = *(const unsigned*)(hin + (long)E1.x * K2);
        unsigned u2 = *(const unsigned*)(hin + (long)E2.x * K2);
        unsigned u3 = *(const unsigned*)(hin + (long)E3.x * K2);
        float2 w0 = decw(E0.y), w1 = decw(E1.y), w2 = decw(E2.y), w3 = decw(E3.y);
        float x0l = bf2f((unsigned short)u0), x0h = bf2f((unsigned short)(u0 >> 16));
        float x1l = bf2f((unsigned short)u1), x1h = bf2f((unsigned short)(u1 >> 16));
        float x2l = bf2f((unsigned short)u2), x2h = bf2f((unsigned short)(u2 >> 16));
        float x3l = bf2f((unsigned short)u3), x3h = bf2f((unsigned short)(u3 >> 16));
        a00 += x0l * w0.x; a01 += x0h * w0.x; a10 += x0l * w0.y; a11 += x0h * w0.y;
        c00 += x1l * w1.x; c01 += x1h * w1.x; c10 += x1l * w1.y; c11 += x1h * w1.y;
        a00 += x2l * w2.x; a01 += x2h * w2.x; a10 += x2l * w2.y; a11 += x2h * w2.y;
        c00 += x3l * w3.x; c01 += x3h * w3.x; c10 += x3l * w3.y; c11 += x3h * w3.y;
    }
    for (; p < p1; ++p) {
        int2 E0 = ed8[p];
        unsigned u0 = *(const unsigned*)(hin + (long)E0.x * K2);
        float2 w0 = decw(E0.y);
        float xl = bf2f((unsigned short)u0), xh = bf2f((unsigned short)(u0 >> 16));
        a00 += xl * w0.x; a01 += xh * w0.x; a10 += xl * w0.y; a11 += xh * w0.y;
    }
    a00 += c00; a01 += c01; a10 += c10; a11 += c11;

    unsigned short* ob = hb + (long)node * K2 + OFFB + lane * 2;
    *(unsigned*)ob       = packbf2(a00, a01);
    *(unsigned*)(ob + D) = packbf2(a10, a11);
}

// ---- GEMM1 via MFMA, BK=32 2-phase dbuf (32KB LDS -> 4-5 blocks/CU) + XCD swz ----
#define STAGE_G1(kb, AL, BL) do { \
    _Pragma("unroll") \
    for (int i_ = 0; i_ < 2; ++i_) { \
        int tt = i_ * 256 + t; \
        int r = tt >> 2, s_ = tt & 3, c = s_ ^ (r & 3); \
        GLDS16(hb  + (long)(m0 + r) * K2 + (kb) + c * 8, (AL) + tt * 8); \
        GLDS16(W1b + (long)(n0 + r) * K2 + (kb) + c * 8, (BL) + tt * 8); \
    } } while (0)

__global__ __launch_bounds__(256) void k_gemm1_mfma(const unsigned short* __restrict__ hb,
                                                    const unsigned short* __restrict__ W1b,
                                                    const float* __restrict__ b1,
                                                    unsigned short* __restrict__ h1b,
                                                    float* __restrict__ stats) {
    __shared__ unsigned short Al[2][128 * 32];
    __shared__ unsigned short Bl[2][128 * 32];
    const int t = threadIdx.x;
    const int lane = t & 63;
    const int w = t >> 6;
    const int wr = w >> 1, wc = w & 1;
    const int l15 = lane & 15, hi = lane >> 4;

    const int q = G1_NT / 8, rem = G1_NT % 8;     // 195, 4
    int f = blockIdx.x;
    int xcd = f & 7, posi = f >> 3;
    int logical = (xcd < rem ? xcd * (q + 1) : rem * (q + 1) + (xcd - rem) * q) + posi;
    const int m0 = (logical >> 2) * 128;
    const int n0 = (logical & 3) * 128;

    f32x4 acc[4][4] = {};

    STAGE_G1(0, Al[0], Bl[0]);
    __syncthreads();
    int cur = 0;
    for (int kt = 0; kt < 16; ++kt) {
        if (kt < 15) STAGE_G1((kt + 1) * 32, Al[cur ^ 1], Bl[cur ^ 1]);
        __builtin_amdgcn_sched_barrier(0);
        bf16x8 af[4], bfr[4];
        #pragma unroll
        for (int mi = 0; mi < 4; ++mi) {
            int R = wr * 64 + mi * 16 + l15;
            int sc = hi ^ (R & 3);
            af[mi] = *(const bf16x8*)(Al[cur] + R * 32 + sc * 8);
        }
        #pragma unroll
        for (int nj = 0; nj < 4; ++nj) {
            int R = wc * 64 + nj * 16 + l15;
            int sc = hi ^ (R & 3);
            bfr[nj] = *(const bf16x8*)(Bl[cur] + R * 32 + sc * 8);
        }
        #pragma unroll
        for (int mi = 0; mi < 4; ++mi)
            #pragma unroll
            for (int nj = 0; nj < 4; ++nj)
                acc[mi][nj] = __builtin_amdgcn_mfma_f32_16x16x32_bf16(
                    af[mi], bfr[nj], acc[mi][nj], 0, 0, 0);
        __syncthreads();   // drains this iter's prefetch + barrier
        cur ^= 1;
    }

    const int cb = n0 + wc * 64;
    float csum[4] = {0.f, 0.f, 0.f, 0.f};
    float csq[4]  = {0.f, 0.f, 0.f, 0.f};
    #pragma unroll
    for (int mi = 0; mi < 4; ++mi) {
        int rbase = m0 + wr * 64 + mi * 16 + hi * 4;
        #pragma unroll
        for (int nj = 0; nj < 4; ++nj) {
            int col = cb + nj * 16 + l15;
            float bias = b1[col];
            #pragma unroll
            for (int r = 0; r < 4; ++r) {
                int row = rbase + r;
                float v = acc[mi][nj][r] + bias;
                v = v > 0.f ? v : 0.2f * v;
                h1b[(long)row * HID + col] = f2bf(v);
                if (row < N_NODES) {
                    csum[nj] += v;
                    csq[nj]  += v * v;
                }
            }
        }
    }
    #pragma unroll
    for (int nj = 0; nj < 4; ++nj) {
        float s = csum[nj], qq = csq[nj];
        s += __shfl_xor(s, 16); qq += __shfl_xor(qq, 16);
        s += __shfl_xor(s, 32); qq += __shfl_xor(qq, 32);
        if (lane < 16) {
            int col = cb + nj * 16 + lane;
            atomicAdd(&stats[col], s);
            atomicAdd(&stats[HID + col], qq);
        }
    }
}

// ---- fold BN into W2 (parallel: one block per W2 row) ----------------------------
__global__ __launch_bounds__(256) void k_fold2(const float* __restrict__ stats,
                                               const float* __restrict__ gamma,
                                               const float* __restrict__ beta,
                                               const float* __restrict__ W2,
                                               const float* __restrict__ b2,
                                               unsigned short* __restrict__ W2b,
                                               float* __restrict__ b2f) {
    __shared__ float scale[HID], shift[HID];
    __shared__ float red[4];
    const int t = threadIdx.x;
    const int j = blockIdx.x;                     // 0..63
    #pragma unroll
    for (int kk = 0; kk < 2; ++kk) {
        int k = t + kk * 256;
        float mu  = stats[k] * (1.f / N_NODES);
        float var = stats[HID + k] * (1.f / N_NODES) - mu * mu;
        var = fmaxf(var, 0.f);
        float sc = gamma[k] * rsqrtf(var + 1e-5f);
        scale[k] = sc;
        shift[k] = beta[k] - mu * sc;
    }
    __syncthreads();
    float part = 0.f;
    #pragma unroll
    for (int kk = 0; kk < 2; ++kk) {
        int k = t + kk * 256;
        float wv = W2[j * HID + k];
        W2b[j * HID + k] = f2bf(wv * scale[k]);
        part += wv * shift[k];
    }
    part += __shfl_xor(part, 1);  part += __shfl_xor(part, 2);
    part += __shfl_xor(part, 4);  part += __shfl_xor(part, 8);
    part += __shfl_xor(part, 16); part += __shfl_xor(part, 32);
    if ((t & 63) == 0) red[t >> 6] = part;
    __syncthreads();
    if (t == 0) b2f[j] = b2[j] + red[0] + red[1] + red[2] + red[3];
}

// ---- head via MFMA, 2-phase prefetch dbuf ----------------------------------------
#define STAGE_HD(kb, AL, BL) do { \
    _Pragma("unroll") \
    for (int i_ = 0; i_ < 4; ++i_) { \
        int tt = i_ * 256 + t; \
        int r = tt >> 3, s_ = tt & 7, c = s_ ^ (r & 7); \
        GLDS16(h1b + (long)(m0 + r) * HID + (kb) + c * 8, (AL) + tt * 8); \
    } \
    _Pragma("unroll") \
    for (int i_ = 0; i_ < 2; ++i_) { \
        int tt = i_ * 256 + t; \
        int r = tt >> 3, s_ = tt & 7, c = s_ ^ (r & 7); \
        GLDS16(W2b + (long)r * HID + (kb) + c * 8, (BL) + tt * 8); \
    } } while (0)

__global__ __launch_bounds__(256) void k_head_mfma(const unsigned short* __restrict__ h1b,
                                                   const unsigned short* __restrict__ W2b,
                                                   const float* __restrict__ b2f,
                                                   const float* __restrict__ Wd,
                                                   const float* __restrict__ bd,
                                                   float* __restrict__ out) {
    __shared__ unsigned short Al[2][128 * 64];   // Al[0] reused as z_lds in epilogue
    __shared__ unsigned short Bl[2][64 * 64];
    __shared__ unsigned short WdL[16 * 64];
    const int t = threadIdx.x;
    const int lane = t & 63;
    const int w = t >> 6;
    const int l15 = lane & 15, hi = lane >> 4;
    const int m0 = blockIdx.x * 128;

    for (int i = t; i < 16 * 64; i += 256) {
        int r = i >> 6, c = i & 63;
        WdL[r * 64 + (((c >> 3) ^ (r & 7)) << 3) + (c & 7)] = f2bf(Wd[i]);
    }

    f32x4 acc[2][4] = {};

    STAGE_HD(0, Al[0], Bl[0]);
    __syncthreads();
    int cur = 0;
    for (int kt = 0; kt < 8; ++kt) {
        if (kt < 7) STAGE_HD((kt + 1) * 64, Al[cur ^ 1], Bl[cur ^ 1]);
        __builtin_amdgcn_sched_barrier(0);
        #pragma unroll
        for (int ks = 0; ks < 2; ++ks) {
            bf16x8 af[2], bfr[4];
            #pragma unroll
            for (int mi = 0; mi < 2; ++mi) {
                int R = w * 32 + mi * 16 + l15;
                int sc = (ks * 4 + hi) ^ (R & 7);
                af[mi] = *(const bf16x8*)(Al[cur] + R * 64 + sc * 8);
            }
            #pragma unroll
            for (int nj = 0; nj < 4; ++nj) {
                int R = nj * 16 + l15;
                int sc = (ks * 4 + hi) ^ (R & 7);
                bfr[nj] = *(const bf16x8*)(Bl[cur] + R * 64 + sc * 8);
            }
            #pragma unroll
            for (int mi = 0; mi < 2; ++mi)
                #pragma unroll
                for (int nj = 0; nj < 4; ++nj)
                    acc[mi][nj] = __builtin_amdgcn_mfma_f32_16x16x32_bf16(
                        af[mi], bfr[nj], acc[mi][nj], 0, 0, 0);
        }
        __syncthreads();
        cur ^= 1;
    }

    float bias[4];
    #pragma unroll
    for (int nj = 0; nj < 4; ++nj) bias[nj] = b2f[nj * 16 + l15];

    float rn[2][4];
    #pragma unroll
    for (int mi = 0; mi < 2; ++mi)
        #pragma unroll
        for (int r = 0; r < 4; ++r) {
            float ss = 0.f;
            #pragma unroll
            for (int nj = 0; nj < 4; ++nj) {
                float v = acc[mi][nj][r] + bias[nj];
                acc[mi][nj][r] = v;
                ss += v * v;
            }
            ss += __shfl_xor(ss, 1); ss += __shfl_xor(ss, 2);
            ss += __shfl_xor(ss, 4); ss += __shfl_xor(ss, 8);
            rn[mi][r] = 1.f / fmaxf(sqrtf(ss), 1e-12f);
        }

    unsigned short* zl = Al[0];
    #pragma unroll
    for (int mi = 0; mi < 2; ++mi)
        #pragma unroll
        for (int r = 0; r < 4; ++r) {
            int lr = w * 32 + mi * 16 + hi * 4 + r;
            int grow = m0 + lr;
            float rnv = rn[mi][r];
            #pragma unroll
            for (int nj = 0; nj < 4; ++nj) {
                int c = nj * 16 + l15;
                float v = acc[mi][nj][r];
                zl[lr * 64 + (((c >> 3) ^ (lr & 7)) << 3) + (c & 7)] = f2bf(v);
                if (grow < N_NODES) out[(long)grow * OUT_DIM + c] = v * rnv;
            }
        }
    __syncthreads();

    f32x4 racc[2] = {};
    #pragma unroll
    for (int mi = 0; mi < 2; ++mi)
        #pragma unroll
        for (int ks = 0; ks < 2; ++ks) {
            int R = w * 32 + mi * 16 + l15;
            int sc = (ks * 4 + hi) ^ (R & 7);
            bf16x8 az = *(const bf16x8*)(zl + R * 64 + sc * 8);
            int scb = (ks * 4 + hi) ^ (l15 & 7);
            bf16x8 bz = *(const bf16x8*)(WdL + l15 * 64 + scb * 8);
            racc[mi] = __builtin_amdgcn_mfma_f32_16x16x32_bf16(az, bz, racc[mi], 0, 0, 0);
        }
    const float bdv = bd[l15];
    #pragma unroll
    for (int mi = 0; mi < 2; ++mi)
        #pragma unroll
        for (int r = 0; r < 4; ++r) {
            int grow = m0 + w * 32 + mi * 16 + hi * 4 + r;
            if (grow < N_NODES)
                out[(long)N_NODES * OUT_DIM + (long)grow * RDIM + l15] = racc[mi][r] + bdv;
        }
}

extern "C" void kernel_launch(void* const* d_in, const int* in_sizes, int n_in,
                              void* d_out, int out_size, void* d_ws, size_t ws_size,
                              hipStream_t stream) {
    const float* feat  = (const float*)d_in[0];
    const int*   ei    = (const int*)  d_in[1];
    const float* ew    = (const float*)d_in[2];
    const int*   et    = (const int*)  d_in[3];
    const float* W1    = (const float*)d_in[4];
    const float* b1    = (const float*)d_in[5];
    const float* gamma = (const float*)d_in[6];
    const float* beta  = (const float*)d_in[7];
    const float* W2    = (const float*)d_in[8];
    const float* b2    = (const float*)d_in[9];
    const float* Wd    = (const float*)d_in[10];
    const float* bd    = (const float*)d_in[11];
    float* out = (float*)d_out;

    unsigned short* hb    = (unsigned short*)d_ws;               // [MP][512] bf16
    unsigned short* h1b   = hb + (long)MP * K2;                  // [MP][512] bf16
    float*          stats = (float*)(h1b + (long)MP * K2);       // 1024
    unsigned short* W2b   = (unsigned short*)(stats + 1024);     // [64][512] bf16
    float*          b2f   = (float*)(W2b + OUT_DIM * HID);       // 64
    int*            bsum  = (int*)(b2f + 64);                    // 256
    int*            boff  = bsum + 256;                          // 256
    unsigned short* W1b   = (unsigned short*)(boff + 256);       // [512][512] bf16

    // CSR scratch aliased onto h1b region (dead once gathers finish)
    int*    deg    = (int*)h1b;
    int*    rowptr = deg + 50008;
    int2*   ed8    = (int2*)(rowptr + 50008);    // 8B aligned (100016 ints offset)
    int*    rank   = (int*)(ed8 + NEDGE);

    k_init<<<(MP * IN_DIM + 255) / 256, 256, 0, stream>>>(feat, W1, hb, W1b, stats, deg);
    k_hist<<<(NEDGE + 255) / 256, 256, 0, stream>>>(ei, deg, rank);
    k_scanA<<<SCAN_B, 256, 0, stream>>>(deg, bsum);
    k_scanB<<<1, 256, 0, stream>>>(bsum, boff);
    k_scanC<<<SCAN_B, 256, 0, stream>>>(deg, boff, rowptr);
    k_scat<<<(NEDGE + 255) / 256, 256, 0, stream>>>(ei, ew, et, rank, rowptr, ed8);

    k_gather_bf<16,    0,  16,  8><<<(N_NODES * 8  + 255) / 256, 256, 0, stream>>>(rowptr, ed8, hb);
    k_gather_bf<32,   16,  48, 16><<<(N_NODES * 16 + 255) / 256, 256, 0, stream>>>(rowptr, ed8, hb);
    k_gather_bf<64,   48, 112, 32><<<(N_NODES * 32 + 255) / 256, 256, 0, stream>>>(rowptr, ed8, hb);
    k_gather_bf<128, 112, 240, 64><<<(N_NODES * 64 + 255) / 256, 256, 0, stream>>>(rowptr, ed8, hb);

    k_gemm1_mfma<<<G1_NT, 256, 0, stream>>>(hb, W1b, b1, h1b, stats);

    k_fold2<<<OUT_DIM, 256, 0, stream>>>(stats, gamma, beta, W2, b2, W2b, b2f);

    k_head_mfma<<<MP / 128, 256, 0, stream>>>(h1b, W2b, b2f, Wd, bd, out);
}

// Round 10
// 326.637 us; speedup vs baseline: 1.0281x; 1.0281x over previous
//
#include <hip/hip_runtime.h>

#define N_NODES   50000
#define MP        50048          // rows padded to 128
#define IN_DIM    16
#define CONCAT    496
#define K2        512            // padded K for GEMM1
#define HID       512
#define OUT_DIM   64
#define RDIM      16
#define NEDGE     800000
#define SCAN_B    196            // ceil(50000/256)
#define G1_NT     ((MP / 128) * 4)   // 1564 gemm1 tiles

typedef __attribute__((ext_vector_type(8))) short bf16x8;
typedef __attribute__((ext_vector_type(4))) float f32x4;

static __device__ __forceinline__ unsigned short f2bf(float x) {
    union { float f; unsigned u; } v; v.f = x;
    unsigned r = v.u + 0x7fff + ((v.u >> 16) & 1);
    return (unsigned short)(r >> 16);
}
static __device__ __forceinline__ float bf2f(unsigned short b) {
    union { unsigned u; float f; } v; v.u = ((unsigned)b) << 16; return v.f;
}
static __device__ __forceinline__ unsigned packbf2(float a, float b) {
    return (unsigned)f2bf(a) | ((unsigned)f2bf(b) << 16);
}
static __device__ __forceinline__ float2 decw(int wbi) {
    unsigned wb = (unsigned)wbi;
    float w = __uint_as_float(wb & 0x7fffffffu);
    return (wb >> 31) ? make_float2(0.f, w) : make_float2(w, 0.f);
}

#define GLDS16(gp, lp) \
    __builtin_amdgcn_global_load_lds((const __attribute__((address_space(1))) unsigned int*)(gp), \
                                     (__attribute__((address_space(3))) unsigned int*)(lp), 16, 0, 0)

// ---- init: feature -> hb bf16; zero pads/stats/deg; W1 -> bf16 -------------------
__global__ __launch_bounds__(256) void k_init(const float* __restrict__ feat,
                                              const float* __restrict__ W1,
                                              unsigned short* __restrict__ hb,
                                              unsigned short* __restrict__ W1b,
                                              float* __restrict__ stats,
                                              int* __restrict__ deg) {
    int idx = blockIdx.x * blockDim.x + threadIdx.x;
    if (idx < 1024) stats[idx] = 0.f;
    if (idx < N_NODES) deg[idx] = 0;
    if (idx < HID * K2) {                          // W1 -> bf16, K-padded
        int n = idx >> 9, k = idx & 511;
        W1b[idx] = (k < CONCAT) ? f2bf(W1[n * CONCAT + k]) : (unsigned short)0;
    }
    if (idx < (MP - N_NODES) * K2) {               // zero padded rows of hb
        int r = N_NODES + (idx >> 9), c = idx & 511;
        hb[(long)r * K2 + c] = 0;
    }
    if (idx >= MP * IN_DIM) return;
    int n = idx >> 4, c = idx & 15;
    hb[(long)n * K2 + CONCAT + c] = 0;             // K pad cols 496..511
    if (n < N_NODES) hb[(long)n * K2 + c] = f2bf(feat[idx]);
}

// ---- CSR build: hist also emits per-edge rank within its dst bucket --------------
__global__ __launch_bounds__(256) void k_hist(const int* __restrict__ ei,
                                              int* __restrict__ deg,
                                              int* __restrict__ rank) {
    int e = blockIdx.x * blockDim.x + threadIdx.x;
    if (e < NEDGE) rank[e] = atomicAdd(&deg[ei[NEDGE + e]], 1);
}

__global__ __launch_bounds__(256) void k_scanA(const int* __restrict__ deg,
                                               int* __restrict__ bsum) {
    __shared__ int red[256];
    int t = threadIdx.x;
    int i = blockIdx.x * 256 + t;
    red[t] = (i < N_NODES) ? deg[i] : 0;
    __syncthreads();
    for (int d = 128; d > 0; d >>= 1) {
        if (t < d) red[t] += red[t + d];
        __syncthreads();
    }
    if (t == 0) bsum[blockIdx.x] = red[0];
}

__global__ __launch_bounds__(256) void k_scanB(const int* __restrict__ bsum,
                                               int* __restrict__ boff) {
    __shared__ int s[256];
    int t = threadIdx.x;
    s[t] = (t < SCAN_B) ? bsum[t] : 0;
    __syncthreads();
    for (int d = 1; d < 256; d <<= 1) {
        int v = (t >= d) ? s[t - d] : 0;
        __syncthreads();
        s[t] += v;
        __syncthreads();
    }
    boff[t] = (t > 0) ? s[t - 1] : 0;
}

__global__ __launch_bounds__(256) void k_scanC(const int* __restrict__ deg,
                                               const int* __restrict__ boff,
                                               int* __restrict__ rowptr) {
    __shared__ int s[256];
    int t = threadIdx.x;
    int i = blockIdx.x * 256 + t;
    int v = (i < N_NODES) ? deg[i] : 0;
    s[t] = v;
    __syncthreads();
    for (int d = 1; d < 256; d <<= 1) {
        int x = (t >= d) ? s[t - d] : 0;
        __syncthreads();
        s[t] += x;
        __syncthreads();
    }
    int excl = s[t] - v + boff[blockIdx.x];
    if (i < N_NODES) rowptr[i] = excl;
    if (i == N_NODES - 1) rowptr[N_NODES] = excl + v;
}

// ---- edge scatter: pos = rowptr[dst] + rank[e]; 8B packed record -----------------
__global__ __launch_bounds__(256) void k_scat(const int* __restrict__ ei,
                                              const float* __restrict__ ew,
                                              const int* __restrict__ et,
                                              const int* __restrict__ rank,
                                              const int* __restrict__ rowptr,
                                              int2* __restrict__ ed8) {
    int e = blockIdx.x * blockDim.x + threadIdx.x;
    if (e >= NEDGE) return;
    int dst = ei[NEDGE + e];
    unsigned wb = (__float_as_uint(ew[e]) & 0x7fffffffu) | ((unsigned)et[e] << 31);
    ed8[rowptr[dst] + rank[e]] = make_int2(ei[e], (int)wb);
}

// ---- gather (bf16 in/out): G lanes per dst, 2 bf16/lane (4B packed); unroll-4 ----
template<int D, int OFF_IN, int OFFB, int G>
__global__ __launch_bounds__(256) void k_gather_bf(const int* __restrict__ rowptr,
                                                   const int2* __restrict__ ed8,
                                                   unsigned short* __restrict__ hb) {
    const int NPB = 256 / G;
    int node = blockIdx.x * NPB + threadIdx.x / G;
    if (node >= N_NODES) return;
    int lane = threadIdx.x % G;
    int p0 = rowptr[node], p1 = rowptr[node + 1];
    float a00 = 0.f, a01 = 0.f, a10 = 0.f, a11 = 0.f;   // a{type}{elem}
    float c00 = 0.f, c01 = 0.f, c10 = 0.f, c11 = 0.f;
    const unsigned short* hin = hb + OFF_IN + lane * 2;
    int p = p0;
    for (; p + 4 <= p1; p += 4) {
        int2 E0 = ed8[p], E1 = ed8[p + 1], E2 = ed8[p + 2], E3 = ed8[p + 3];
        unsigned u0 = *(const unsigned*)(hin + (long)E0.x * K2);
        unsigned u1 = *(const unsigned*)(hin + (long)E1.x * K2);
        unsigned u2 = *(const unsigned*)(hin + (long)E2.x * K2);
        unsigned u3 = *(const unsigned*)(hin + (long)E3.x * K2);
        float2 w0 = decw(E0.y), w1 = decw(E1.y), w2 = decw(E2.y), w3 = decw(E3.y);
        float x0l = bf2f((unsigned short)u0), x0h = bf2f((unsigned short)(u0 >> 16));
        float x1l = bf2f((unsigned short)u1), x1h = bf2f((unsigned short)(u1 >> 16));
        float x2l = bf2f((unsigned short)u2), x2h = bf2f((unsigned short)(u2 >> 16));
        float x3l = bf2f((unsigned short)u3), x3h = bf2f((unsigned short)(u3 >> 16));
        a00 += x0l * w0.x; a01 += x0h * w0.x; a10 += x0l * w0.y; a11 += x0h * w0.y;
        c00 += x1l * w1.x; c01 += x1h * w1.x; c10 += x1l * w1.y; c11 += x1h * w1.y;
        a00 += x2l * w2.x; a01 += x2h * w2.x; a10 += x2l * w2.y; a11 += x2h * w2.y;
        c00 += x3l * w3.x; c01 += x3h * w3.x; c10 += x3l * w3.y; c11 += x3h * w3.y;
    }
    for (; p < p1; ++p) {
        int2 E0 = ed8[p];
        unsigned u0 = *(const unsigned*)(hin + (long)E0.x * K2);
        float2 w0 = decw(E0.y);
        float xl = bf2f((unsigned short)u0), xh = bf2f((unsigned short)(u0 >> 16));
        a00 += xl * w0.x; a01 += xh * w0.x; a10 += xl * w0.y; a11 += xh * w0.y;
    }
    a00 += c00; a01 += c01; a10 += c10; a11 += c11;

    unsigned short* ob = hb + (long)node * K2 + OFFB + lane * 2;
    *(unsigned*)ob       = packbf2(a00, a01);
    *(unsigned*)(ob + D) = packbf2(a10, a11);
}

// ---- GEMM1 via MFMA: BK=64 2-phase dbuf, 8 waves (2Mx4N), XCD swizzle ------------
#define STAGE_G1(kb, AL, BL) do { \
    _Pragma("unroll") \
    for (int i_ = 0; i_ < 2; ++i_) { \
        int tt = i_ * 512 + t; \
        int r = tt >> 3, s_ = tt & 7, c = s_ ^ (r & 7); \
        GLDS16(hb  + (long)(m0 + r) * K2 + (kb) + c * 8, (AL) + tt * 8); \
        GLDS16(W1b + (long)(n0 + r) * K2 + (kb) + c * 8, (BL) + tt * 8); \
    } } while (0)

__global__ __launch_bounds__(512) void k_gemm1_mfma(const unsigned short* __restrict__ hb,
                                                    const unsigned short* __restrict__ W1b,
                                                    const float* __restrict__ b1,
                                                    unsigned short* __restrict__ h1b,
                                                    float* __restrict__ stats) {
    __shared__ unsigned short Al[2][128 * 64];
    __shared__ unsigned short Bl[2][128 * 64];
    const int t = threadIdx.x;
    const int lane = t & 63;
    const int w = t >> 6;              // 0..7
    const int wr = w >> 2, wc = w & 3; // 2 x 4 wave grid; wave tile 64x32
    const int l15 = lane & 15, hi = lane >> 4;

    const int q = G1_NT / 8, rem = G1_NT % 8;     // 195, 4
    int f = blockIdx.x;
    int xcd = f & 7, posi = f >> 3;
    int logical = (xcd < rem ? xcd * (q + 1) : rem * (q + 1) + (xcd - rem) * q) + posi;
    const int m0 = (logical >> 2) * 128;
    const int n0 = (logical & 3) * 128;

    f32x4 acc[4][2] = {};

    STAGE_G1(0, Al[0], Bl[0]);
    __syncthreads();
    int cur = 0;
    for (int kt = 0; kt < 8; ++kt) {
        if (kt < 7) STAGE_G1((kt + 1) * 64, Al[cur ^ 1], Bl[cur ^ 1]);
        __builtin_amdgcn_sched_barrier(0);
        #pragma unroll
        for (int ks = 0; ks < 2; ++ks) {
            bf16x8 af[4], bfr[2];
            #pragma unroll
            for (int mi = 0; mi < 4; ++mi) {
                int R = wr * 64 + mi * 16 + l15;
                int sc = (ks * 4 + hi) ^ (R & 7);
                af[mi] = *(const bf16x8*)(Al[cur] + R * 64 + sc * 8);
            }
            #pragma unroll
            for (int nj = 0; nj < 2; ++nj) {
                int R = wc * 32 + nj * 16 + l15;
                int sc = (ks * 4 + hi) ^ (R & 7);
                bfr[nj] = *(const bf16x8*)(Bl[cur] + R * 64 + sc * 8);
            }
            #pragma unroll
            for (int mi = 0; mi < 4; ++mi)
                #pragma unroll
                for (int nj = 0; nj < 2; ++nj)
                    acc[mi][nj] = __builtin_amdgcn_mfma_f32_16x16x32_bf16(
                        af[mi], bfr[nj], acc[mi][nj], 0, 0, 0);
        }
        __syncthreads();   // drains this iter's prefetch + barrier
        cur ^= 1;
    }

    const int cb = n0 + wc * 32;
    float csum[2] = {0.f, 0.f};
    float csq[2]  = {0.f, 0.f};
    #pragma unroll
    for (int mi = 0; mi < 4; ++mi) {
        int rbase = m0 + wr * 64 + mi * 16 + hi * 4;
        #pragma unroll
        for (int nj = 0; nj < 2; ++nj) {
            int col = cb + nj * 16 + l15;
            float bias = b1[col];
            #pragma unroll
            for (int r = 0; r < 4; ++r) {
                int row = rbase + r;
                float v = acc[mi][nj][r] + bias;
                v = v > 0.f ? v : 0.2f * v;
                h1b[(long)row * HID + col] = f2bf(v);
                if (row < N_NODES) {
                    csum[nj] += v;
                    csq[nj]  += v * v;
                }
            }
        }
    }
    #pragma unroll
    for (int nj = 0; nj < 2; ++nj) {
        float s = csum[nj], qq = csq[nj];
        s += __shfl_xor(s, 16); qq += __shfl_xor(qq, 16);
        s += __shfl_xor(s, 32); qq += __shfl_xor(qq, 32);
        if (lane < 16) {
            int col = cb + nj * 16 + lane;
            atomicAdd(&stats[col], s);
            atomicAdd(&stats[HID + col], qq);
        }
    }
}

// ---- fold BN into W2 (parallel: one block per W2 row) ----------------------------
__global__ __launch_bounds__(256) void k_fold2(const float* __restrict__ stats,
                                               const float* __restrict__ gamma,
                                               const float* __restrict__ beta,
                                               const float* __restrict__ W2,
                                               const float* __restrict__ b2,
                                               unsigned short* __restrict__ W2b,
                                               float* __restrict__ b2f) {
    __shared__ float scale[HID], shift[HID];
    __shared__ float red[4];
    const int t = threadIdx.x;
    const int j = blockIdx.x;                     // 0..63
    #pragma unroll
    for (int kk = 0; kk < 2; ++kk) {
        int k = t + kk * 256;
        float mu  = stats[k] * (1.f / N_NODES);
        float var = stats[HID + k] * (1.f / N_NODES) - mu * mu;
        var = fmaxf(var, 0.f);
        float sc = gamma[k] * rsqrtf(var + 1e-5f);
        scale[k] = sc;
        shift[k] = beta[k] - mu * sc;
    }
    __syncthreads();
    float part = 0.f;
    #pragma unroll
    for (int kk = 0; kk < 2; ++kk) {
        int k = t + kk * 256;
        float wv = W2[j * HID + k];
        W2b[j * HID + k] = f2bf(wv * scale[k]);
        part += wv * shift[k];
    }
    part += __shfl_xor(part, 1);  part += __shfl_xor(part, 2);
    part += __shfl_xor(part, 4);  part += __shfl_xor(part, 8);
    part += __shfl_xor(part, 16); part += __shfl_xor(part, 32);
    if ((t & 63) == 0) red[t >> 6] = part;
    __syncthreads();
    if (t == 0) b2f[j] = b2[j] + red[0] + red[1] + red[2] + red[3];
}

// ---- head via MFMA, 2-phase prefetch dbuf ----------------------------------------
#define STAGE_HD(kb, AL, BL) do { \
    _Pragma("unroll") \
    for (int i_ = 0; i_ < 4; ++i_) { \
        int tt = i_ * 256 + t; \
        int r = tt >> 3, s_ = tt & 7, c = s_ ^ (r & 7); \
        GLDS16(h1b + (long)(m0 + r) * HID + (kb) + c * 8, (AL) + tt * 8); \
    } \
    _Pragma("unroll") \
    for (int i_ = 0; i_ < 2; ++i_) { \
        int tt = i_ * 256 + t; \
        int r = tt >> 3, s_ = tt & 7, c = s_ ^ (r & 7); \
        GLDS16(W2b + (long)r * HID + (kb) + c * 8, (BL) + tt * 8); \
    } } while (0)

__global__ __launch_bounds__(256) void k_head_mfma(const unsigned short* __restrict__ h1b,
                                                   const unsigned short* __restrict__ W2b,
                                                   const float* __restrict__ b2f,
                                                   const float* __restrict__ Wd,
                                                   const float* __restrict__ bd,
                                                   float* __restrict__ out) {
    __shared__ unsigned short Al[2][128 * 64];   // Al[0] reused as z_lds in epilogue
    __shared__ unsigned short Bl[2][64 * 64];
    __shared__ unsigned short WdL[16 * 64];
    const int t = threadIdx.x;
    const int lane = t & 63;
    const int w = t >> 6;
    const int l15 = lane & 15, hi = lane >> 4;
    const int m0 = blockIdx.x * 128;

    for (int i = t; i < 16 * 64; i += 256) {
        int r = i >> 6, c = i & 63;
        WdL[r * 64 + (((c >> 3) ^ (r & 7)) << 3) + (c & 7)] = f2bf(Wd[i]);
    }

    f32x4 acc[2][4] = {};

    STAGE_HD(0, Al[0], Bl[0]);
    __syncthreads();
    int cur = 0;
    for (int kt = 0; kt < 8; ++kt) {
        if (kt < 7) STAGE_HD((kt + 1) * 64, Al[cur ^ 1], Bl[cur ^ 1]);
        __builtin_amdgcn_sched_barrier(0);
        #pragma unroll
        for (int ks = 0; ks < 2; ++ks) {
            bf16x8 af[2], bfr[4];
            #pragma unroll
            for (int mi = 0; mi < 2; ++mi) {
                int R = w * 32 + mi * 16 + l15;
                int sc = (ks * 4 + hi) ^ (R & 7);
                af[mi] = *(const bf16x8*)(Al[cur] + R * 64 + sc * 8);
            }
            #pragma unroll
            for (int nj = 0; nj < 4; ++nj) {
                int R = nj * 16 + l15;
                int sc = (ks * 4 + hi) ^ (R & 7);
                bfr[nj] = *(const bf16x8*)(Bl[cur] + R * 64 + sc * 8);
            }
            #pragma unroll
            for (int mi = 0; mi < 2; ++mi)
                #pragma unroll
                for (int nj = 0; nj < 4; ++nj)
                    acc[mi][nj] = __builtin_amdgcn_mfma_f32_16x16x32_bf16(
                        af[mi], bfr[nj], acc[mi][nj], 0, 0, 0);
        }
        __syncthreads();
        cur ^= 1;
    }

    float bias[4];
    #pragma unroll
    for (int nj = 0; nj < 4; ++nj) bias[nj] = b2f[nj * 16 + l15];

    float rn[2][4];
    #pragma unroll
    for (int mi = 0; mi < 2; ++mi)
        #pragma unroll
        for (int r = 0; r < 4; ++r) {
            float ss = 0.f;
            #pragma unroll
            for (int nj = 0; nj < 4; ++nj) {
                float v = acc[mi][nj][r] + bias[nj];
                acc[mi][nj][r] = v;
                ss += v * v;
            }
            ss += __shfl_xor(ss, 1); ss += __shfl_xor(ss, 2);
            ss += __shfl_xor(ss, 4); ss += __shfl_xor(ss, 8);
            rn[mi][r] = 1.f / fmaxf(sqrtf(ss), 1e-12f);
        }

    unsigned short* zl = Al[0];
    #pragma unroll
    for (int mi = 0; mi < 2; ++mi)
        #pragma unroll
        for (int r = 0; r < 4; ++r) {
            int lr = w * 32 + mi * 16 + hi * 4 + r;
            int grow = m0 + lr;
            float rnv = rn[mi][r];
            #pragma unroll
            for (int nj = 0; nj < 4; ++nj) {
                int c = nj * 16 + l15;
                float v = acc[mi][nj][r];
                zl[lr * 64 + (((c >> 3) ^ (lr & 7)) << 3) + (c & 7)] = f2bf(v);
                if (grow < N_NODES) out[(long)grow * OUT_DIM + c] = v * rnv;
            }
        }
    __syncthreads();

    f32x4 racc[2] = {};
    #pragma unroll
    for (int mi = 0; mi < 2; ++mi)
        #pragma unroll
        for (int ks = 0; ks < 2; ++ks) {
            int R = w * 32 + mi * 16 + l15;
            int sc = (ks * 4 + hi) ^ (R & 7);
            bf16x8 az = *(const bf16x8*)(zl + R * 64 + sc * 8);
            int scb = (ks * 4 + hi) ^ (l15 & 7);
            bf16x8 bz = *(const bf16x8*)(WdL + l15 * 64 + scb * 8);
            racc[mi] = __builtin_amdgcn_mfma_f32_16x16x32_bf16(az, bz, racc[mi], 0, 0, 0);
        }
    const float bdv = bd[l15];
    #pragma unroll
    for (int mi = 0; mi < 2; ++mi)
        #pragma unroll
        for (int r = 0; r < 4; ++r) {
            int grow = m0 + w * 32 + mi * 16 + hi * 4 + r;
            if (grow < N_NODES)
                out[(long)N_NODES * OUT_DIM + (long)grow * RDIM + l15] = racc[mi][r] + bdv;
        }
}

extern "C" void kernel_launch(void* const* d_in, const int* in_sizes, int n_in,
                              void* d_out, int out_size, void* d_ws, size_t ws_size,
                              hipStream_t stream) {
    const float* feat  = (const float*)d_in[0];
    const int*   ei    = (const int*)  d_in[1];
    const float* ew    = (const float*)d_in[2];
    const int*   et    = (const int*)  d_in[3];
    const float* W1    = (const float*)d_in[4];
    const float* b1    = (const float*)d_in[5];
    const float* gamma = (const float*)d_in[6];
    const float* beta  = (const float*)d_in[7];
    const float* W2    = (const float*)d_in[8];
    const float* b2    = (const float*)d_in[9];
    const float* Wd    = (const float*)d_in[10];
    const float* bd    = (const float*)d_in[11];
    float* out = (float*)d_out;

    unsigned short* hb    = (unsigned short*)d_ws;               // [MP][512] bf16
    unsigned short* h1b   = hb + (long)MP * K2;                  // [MP][512] bf16
    float*          stats = (float*)(h1b + (long)MP * K2);       // 1024
    unsigned short* W2b   = (unsigned short*)(stats + 1024);     // [64][512] bf16
    float*          b2f   = (float*)(W2b + OUT_DIM * HID);       // 64
    int*            bsum  = (int*)(b2f + 64);                    // 256
    int*            boff  = bsum + 256;                          // 256
    unsigned short* W1b   = (unsigned short*)(boff + 256);       // [512][512] bf16

    // CSR scratch aliased onto h1b region (dead once gathers finish)
    int*    deg    = (int*)h1b;
    int*    rowptr = deg + 50008;
    int2*   ed8    = (int2*)(rowptr + 50008);    // 8B aligned (100016 ints offset)
    int*    rank   = (int*)(ed8 + NEDGE);

    k_init<<<(MP * IN_DIM + 255) / 256, 256, 0, stream>>>(feat, W1, hb, W1b, stats, deg);
    k_hist<<<(NEDGE + 255) / 256, 256, 0, stream>>>(ei, deg, rank);
    k_scanA<<<SCAN_B, 256, 0, stream>>>(deg, bsum);
    k_scanB<<<1, 256, 0, stream>>>(bsum, boff);
    k_scanC<<<SCAN_B, 256, 0, stream>>>(deg, boff, rowptr);
    k_scat<<<(NEDGE + 255) / 256, 256, 0, stream>>>(ei, ew, et, rank, rowptr, ed8);

    k_gather_bf<16,    0,  16,  8><<<(N_NODES * 8  + 255) / 256, 256, 0, stream>>>(rowptr, ed8, hb);
    k_gather_bf<32,   16,  48, 16><<<(N_NODES * 16 + 255) / 256, 256, 0, stream>>>(rowptr, ed8, hb);
    k_gather_bf<64,   48, 112, 32><<<(N_NODES * 32 + 255) / 256, 256, 0, stream>>>(rowptr, ed8, hb);
    k_gather_bf<128, 112, 240, 64><<<(N_NODES * 64 + 255) / 256, 256, 0, stream>>>(rowptr, ed8, hb);

    k_gemm1_mfma<<<G1_NT, 512, 0, stream>>>(hb, W1b, b1, h1b, stats);

    k_fold2<<<OUT_DIM, 256, 0, stream>>>(stats, gamma, beta, W2, b2, W2b, b2f);

    k_head_mfma<<<MP / 128, 256, 0, stream>>>(h1b, W2b, b2f, Wd, bd, out);
}